// Round 2
// baseline (3901.929 us; speedup 1.0000x reference)
//
#include <hip/hip_runtime.h>

// Problem constants (must match reference)
#define Nb   256
#define Tt   2048
#define INs  6
#define HID  128
#define STs  64
#define LAY  134   // INs + HID
#define OUTs 6
#define NPAIR 67   // LAY/2
#define NDW  68    // padded dword count (f16x2 units); last dword is zero pad

typedef _Float16 h2 __attribute__((ext_vector_type(2)));
typedef __fp16  f16x2 __attribute__((ext_vector_type(2)));   // builtin-compatible spelling

__device__ __forceinline__ float exp2_fast(float x) {
#if __has_builtin(__builtin_amdgcn_exp2f)
    return __builtin_amdgcn_exp2f(x);
#else
    return exp2f(x);
#endif
}
__device__ __forceinline__ float rcp_fast(float x) {
#if __has_builtin(__builtin_amdgcn_rcpf)
    return __builtin_amdgcn_rcpf(x);
#else
    return 1.0f / x;
#endif
}
// tanh(x) = 1 - 2/(exp2(2*log2e*x)+1); saturates correctly for |x| large
__device__ __forceinline__ float tanh_fast(float x) {
    float e = exp2_fast(x * 2.8853900817779268f);
    return 1.0f - 2.0f * rcp_fast(e + 1.0f);
}
__device__ __forceinline__ unsigned pack2(float a, float b) {
#if __has_builtin(__builtin_amdgcn_cvt_pkrtz)
    union { f16x2 h; unsigned u; } u;
    u.h = __builtin_amdgcn_cvt_pkrtz(a, b);
    return u.u;
#else
    union { h2 h; unsigned u; } u;
    u.h[0] = (_Float16)a; u.h[1] = (_Float16)b;
    return u.u;
#endif
}
__device__ __forceinline__ h2 as_h2(unsigned v) {
    union { unsigned u; h2 h; } u; u.u = v; return u.h;
}
__device__ __forceinline__ float dot2f(h2 a, h2 b, float c) {
#if __has_builtin(__builtin_amdgcn_fdot2)
    union { h2 h; f16x2 f; } ua, ub;
    ua.h = a; ub.h = b;
    return __builtin_amdgcn_fdot2(ua.f, ub.f, c, false);   // v_dot2_f32_f16
#else
    return c + (float)a[0] * (float)b[0] + (float)a[1] * (float)b[1];
#endif
}

// dot over 134 f16 elems (68 packed dwords, last is zero pad) + bias
__device__ __forceinline__ float dotLv(const unsigned* buf, const h2* w, float bias) {
    const uint4* b4 = (const uint4*)buf;
    float a0 = 0.f, a1 = 0.f, a2 = 0.f, a3 = 0.f;
#pragma unroll
    for (int m = 0; m < 17; ++m) {
        uint4 v = b4[m];
        a0 = dot2f(as_h2(v.x), w[4*m+0], a0);
        a1 = dot2f(as_h2(v.y), w[4*m+1], a1);
        a2 = dot2f(as_h2(v.z), w[4*m+2], a2);
        a3 = dot2f(as_h2(v.w), w[4*m+3], a3);
    }
    return ((a0 + a1) + (a2 + a3)) + bias;
}

// projection: out[0..5] = H . Wo[:,o] + bo, one wave (64 lanes), lane l owns H[2l],H[2l+1]
__device__ __forceinline__ void do_proj(const float* Hrow, const float* wo0, const float* wo1,
                                        const float* bo6, float* outp, int l) {
    float hA = Hrow[2*l], hB = Hrow[2*l+1];
    float r[6];
#pragma unroll
    for (int o = 0; o < 6; ++o) r[o] = hA * wo0[o] + hB * wo1[o];
#pragma unroll
    for (int o = 0; o < 6; ++o) {
#pragma unroll
        for (int k = 1; k < 64; k <<= 1) r[o] += __shfl_xor(r[o], k, 64);
    }
    if (l == 0) {
#pragma unroll
        for (int o = 0; o < 6; ++o) outp[o] = r[o] + bo6[o];
    }
}

__global__ __launch_bounds__(1024)
void lmsc_kernel(const float* __restrict__ X,  const float* __restrict__ H0,
                 const float* __restrict__ Wg1, const float* __restrict__ bg1,
                 const float* __restrict__ Wg2, const float* __restrict__ bg2,
                 const float* __restrict__ Wa,  const float* __restrict__ ba,
                 const float* __restrict__ Wb,  const float* __restrict__ bb,
                 const float* __restrict__ Wh,  const float* __restrict__ bh,
                 const float* __restrict__ Wo,  const float* __restrict__ bo,
                 float* __restrict__ out)
{
    __shared__ float Xls[Tt * INs];                 // 48 KB: this row's whole input
    __shared__ alignas(16) unsigned LvX[NDW];       // current Lv, f16x2: [x/n (3dw), H (64dw), pad]
    __shared__ alignas(16) unsigned LvB[NDW];       // inter-layer activations, f16x2
    __shared__ float T1[LAY], T2[LAY];              // tanh outputs of the two gate matrices
    __shared__ float Hf[2][HID];                    // double-buffered hidden state (f32 master)
    __shared__ float Aal[HID], Bbe[HID];
    __shared__ float H0l[STs];
    __shared__ float nrm[2], rnr[2];

    const int tid = threadIdx.x;
    const int n   = blockIdx.x;

    // ---------------- stage X row (coalesced float4) ----------------
    {
        const float4* Xg  = (const float4*)(X + (size_t)n * (Tt * INs));
        float4*       Xl4 = (float4*)Xls;
        for (int i = tid; i < (Tt * INs) / 4; i += 1024) Xl4[i] = Xg[i];
    }
    if (tid < STs) H0l[tid] = H0[n * STs + tid];

    // ---------------- per-thread weight column -> registers (f16 packed, RNE) -------------
    // roles: [0,134) Wg1[0] | [134,268) Wg2[0] | [268,402) Wg1[1] | [402,536) Wg2[1]
    //        [536,664) Wa   | [664,792) Wb     | [800,867) packers | 900 norm | [960,1024) proj
    h2 wreg[NDW];
    float bias = 0.f;
    {
        const float* Wp = nullptr; int od = LAY, j = 0;
        if      (tid < 134) { Wp = Wg1;             j = tid;       bias = bg1[j]; }
        else if (tid < 268) { Wp = Wg2;             j = tid - 134; bias = bg2[j]; }
        else if (tid < 402) { Wp = Wg1 + LAY*LAY;   j = tid - 268; bias = bg1[LAY + j]; }
        else if (tid < 536) { Wp = Wg2 + LAY*LAY;   j = tid - 402; bias = bg2[LAY + j]; }
        else if (tid < 664) { Wp = Wa; od = HID;    j = tid - 536; bias = ba[j]; }
        else if (tid < 792) { Wp = Wb; od = HID;    j = tid - 664; bias = bb[j]; }
        if (Wp) {
            for (int m = 0; m < NPAIR; ++m) {
                float w0 = Wp[(2*m)     * od + j];
                float w1 = Wp[(2*m + 1) * od + j];
                h2 h; h[0] = (_Float16)w0; h[1] = (_Float16)w1;   // RNE
                wreg[m] = h;
            }
            h2 z; z[0] = (_Float16)0.f; z[1] = (_Float16)0.f;
            wreg[NPAIR] = z;
        }
    }
    // projection wave constants
    float wo0[6], wo1[6], bo6[6];
    if (tid >= 960) {
        int l = tid - 960;
#pragma unroll
        for (int o = 0; o < 6; ++o) {
            wo0[o] = Wo[(2*l)     * OUTs + o];
            wo1[o] = Wo[(2*l + 1) * OUTs + o];
            bo6[o] = bo[o];
        }
    }
    __syncthreads();

    // ---------------- init: S0 = H0 @ Wh + bh ; norm_0 ; x-part ; pads ----------------
    if (tid >= 536 && tid < 664) {
        int j = tid - 536;
        float s = bh[j];
        for (int k = 0; k < STs; ++k) s += H0l[k] * Wh[k * HID + j];
        Hf[0][j] = s;
        ((_Float16*)LvX)[6 + j] = (_Float16)s;
    }
    if (tid == 900) {
        float s = 0.f;
#pragma unroll
        for (int i = 0; i < 6; ++i) s += Xls[i] * Xls[i];
        float nv = sqrtf(s);
        float rn = rcp_fast(nv);
        nrm[0] = nv; rnr[0] = rn;
        LvX[0] = pack2(Xls[0]*rn, Xls[1]*rn);
        LvX[1] = pack2(Xls[2]*rn, Xls[3]*rn);
        LvX[2] = pack2(Xls[4]*rn, Xls[5]*rn);
    }
    if (tid == 0) { LvX[NPAIR] = 0u; LvB[NPAIR] = 0u; }
    __syncthreads();

    const float LOG2E = 1.4426950408889634f;

#pragma unroll 1
    for (int t = 0; t < Tt; ++t) {
        const int p = t & 1;
        // ---- P1: gated layer 1 dots ; norm for t+1 ; projection of Y[t-1] ----
        if (tid < 268) {
            float s = dotLv(LvX, wreg, bias);
            float v = tanh_fast(s);
            if (tid < 134) T1[tid] = v; else T2[tid - 134] = v;
        } else if (tid >= 960) {
            if (t > 0)
                do_proj(Hf[p], wo0, wo1, bo6, out + ((size_t)n * Tt + (t - 1)) * OUTs, tid - 960);
        } else if (tid == 900 && (t + 1) < Tt) {
            const float* xp = &Xls[(t + 1) * INs];
            float s = 0.f;
#pragma unroll
            for (int i = 0; i < 6; ++i) s += xp[i] * xp[i];
            float nv = sqrtf(s);
            nrm[(t + 1) & 1] = nv;
            rnr[(t + 1) & 1] = rcp_fast(nv);
        }
        __syncthreads();
        // ---- P2: pack tanh1*tanh2 -> LvB ; write x-part of LvX for t+1 ----
        if (tid >= 800 && tid < 800 + NPAIR) {
            int m = tid - 800;
            float p0 = T1[2*m]     * T2[2*m];
            float p1 = T1[2*m + 1] * T2[2*m + 1];
            LvB[m] = pack2(p0, p1);
        } else if (tid == 900 && (t + 1) < Tt) {
            const float* xp = &Xls[(t + 1) * INs];
            float rn = rnr[(t + 1) & 1];
            LvX[0] = pack2(xp[0]*rn, xp[1]*rn);
            LvX[1] = pack2(xp[2]*rn, xp[3]*rn);
            LvX[2] = pack2(xp[4]*rn, xp[5]*rn);
        }
        __syncthreads();
        // ---- P3: gated layer 2 dots ----
        if (tid >= 268 && tid < 536) {
            float s = dotLv(LvB, wreg, bias);
            float v = tanh_fast(s);
            if (tid < 402) T1[tid - 268] = v; else T2[tid - 402] = v;
        }
        __syncthreads();
        // ---- P4: pack -> LvB ----
        if (tid >= 800 && tid < 800 + NPAIR) {
            int m = tid - 800;
            float p0 = T1[2*m]     * T2[2*m];
            float p1 = T1[2*m + 1] * T2[2*m + 1];
            LvB[m] = pack2(p0, p1);
        }
        __syncthreads();
        // ---- P5: alpha / beta dots ----
        if (tid >= 536 && tid < 792) {
            float s = dotLv(LvB, wreg, bias);
            if (tid < 664) Aal[tid - 536] = exp2_fast(s * LOG2E);   // exp
            else           Bbe[tid - 664] = tanh_fast(s);
        }
        __syncthreads();
        // ---- P6: H update ; refresh H-part of LvX ----
        if (tid < HID) {
            float a = Aal[tid], b = Bbe[tid];
            float h = Hf[p][tid];
            float e = exp2_fast(-a * nrm[p] * LOG2E);
            float hn = e * (h - b) + b;
            Hf[p ^ 1][tid] = hn;
            ((_Float16*)LvX)[6 + tid] = (_Float16)hn;
        }
        __syncthreads();
    }
    // ---- epilogue: project Y[T-1] = H_T (in Hf[Tt & 1] == Hf[0]) ----
    if (tid >= 960)
        do_proj(Hf[Tt & 1], wo0, wo1, bo6, out + ((size_t)n * Tt + (Tt - 1)) * OUTs, tid - 960);
}

extern "C" void kernel_launch(void* const* d_in, const int* in_sizes, int n_in,
                              void* d_out, int out_size, void* d_ws, size_t ws_size,
                              hipStream_t stream) {
    const float* X   = (const float*)d_in[0];
    const float* H0  = (const float*)d_in[1];
    const float* Wg1 = (const float*)d_in[2];
    const float* bg1 = (const float*)d_in[3];
    const float* Wg2 = (const float*)d_in[4];
    const float* bg2 = (const float*)d_in[5];
    const float* Wa  = (const float*)d_in[6];
    const float* ba  = (const float*)d_in[7];
    const float* Wb  = (const float*)d_in[8];
    const float* bb  = (const float*)d_in[9];
    const float* Wh  = (const float*)d_in[10];
    const float* bh  = (const float*)d_in[11];
    const float* Wo  = (const float*)d_in[12];
    const float* bo  = (const float*)d_in[13];
    float* out = (float*)d_out;

    hipLaunchKernelGGL(lmsc_kernel, dim3(Nb), dim3(1024), 0, stream,
                       X, H0, Wg1, bg1, Wg2, bg2, Wa, ba, Wb, bb, Wh, bh, Wo, bo, out);
}

// Round 3
// 3537.141 us; speedup vs baseline: 1.1031x; 1.1031x over previous
//
#include <hip/hip_runtime.h>

// Problem constants (must match reference)
#define Nb   256
#define Tt   2048
#define INs  6
#define HID  128
#define STs  64
#define LAY  134   // INs + HID
#define OUTs 6
#define NPAIR 67   // LAY/2
#define NDW  68    // padded dword count (f16x2 units); last dword is zero pad

typedef _Float16 h2 __attribute__((ext_vector_type(2)));
typedef __fp16  f16x2 __attribute__((ext_vector_type(2)));   // builtin-compatible spelling

__device__ __forceinline__ float exp2_fast(float x) {
#if __has_builtin(__builtin_amdgcn_exp2f)
    return __builtin_amdgcn_exp2f(x);
#else
    return exp2f(x);
#endif
}
__device__ __forceinline__ float rcp_fast(float x) {
#if __has_builtin(__builtin_amdgcn_rcpf)
    return __builtin_amdgcn_rcpf(x);
#else
    return 1.0f / x;
#endif
}
// tanh(x) = 1 - 2/(exp2(2*log2e*x)+1); saturates correctly for |x| large
__device__ __forceinline__ float tanh_fast(float x) {
    float e = exp2_fast(x * 2.8853900817779268f);
    return 1.0f - 2.0f * rcp_fast(e + 1.0f);
}
__device__ __forceinline__ unsigned pack2(float a, float b) {
#if __has_builtin(__builtin_amdgcn_cvt_pkrtz)
    union { f16x2 h; unsigned u; } u;
    u.h = __builtin_amdgcn_cvt_pkrtz(a, b);
    return u.u;
#else
    union { h2 h; unsigned u; } u;
    u.h[0] = (_Float16)a; u.h[1] = (_Float16)b;
    return u.u;
#endif
}
__device__ __forceinline__ h2 as_h2(unsigned v) {
    union { unsigned u; h2 h; } u; u.u = v; return u.h;
}
__device__ __forceinline__ float dot2f(h2 a, h2 b, float c) {
#if __has_builtin(__builtin_amdgcn_fdot2)
    union { h2 h; f16x2 f; } ua, ub;
    ua.h = a; ub.h = b;
    return __builtin_amdgcn_fdot2(ua.f, ub.f, c, false);   // v_dot2_f32_f16
#else
    return c + (float)a[0] * (float)b[0] + (float)a[1] * (float)b[1];
#endif
}

// dual dot over 134 f16 elems (68 packed dwords, last zero pad), shared activation stream
__device__ __forceinline__ void dotLv2(const unsigned* buf, const h2* w1, const h2* w2,
                                       float b1, float b2, float& o1, float& o2) {
    const uint4* b4 = (const uint4*)buf;
    float a0 = 0.f, a1 = 0.f, a2 = 0.f, a3 = 0.f;
    float c0 = 0.f, c1 = 0.f, c2 = 0.f, c3 = 0.f;
#pragma unroll
    for (int m = 0; m < 17; ++m) {
        uint4 v = b4[m];
        h2 vx = as_h2(v.x), vy = as_h2(v.y), vz = as_h2(v.z), vw = as_h2(v.w);
        a0 = dot2f(vx, w1[4*m+0], a0);  c0 = dot2f(vx, w2[4*m+0], c0);
        a1 = dot2f(vy, w1[4*m+1], a1);  c1 = dot2f(vy, w2[4*m+1], c1);
        a2 = dot2f(vz, w1[4*m+2], a2);  c2 = dot2f(vz, w2[4*m+2], c2);
        a3 = dot2f(vw, w1[4*m+3], a3);  c3 = dot2f(vw, w2[4*m+3], c3);
    }
    o1 = ((a0 + a1) + (a2 + a3)) + b1;
    o2 = ((c0 + c1) + (c2 + c3)) + b2;
}

// projection: out[0..5] = H . Wo[:,o] + bo, one full wave, lane l owns H[2l],H[2l+1]
__device__ __forceinline__ void do_proj(const float* Hrow, const float* wo0, const float* wo1,
                                        const float* bo6, float* outp, int l) {
    float hA = Hrow[2*l], hB = Hrow[2*l+1];
    float r[6];
#pragma unroll
    for (int o = 0; o < 6; ++o) r[o] = hA * wo0[o] + hB * wo1[o];
#pragma unroll
    for (int o = 0; o < 6; ++o) {
#pragma unroll
        for (int k = 1; k < 64; k <<= 1) r[o] += __shfl_xor(r[o], k, 64);
    }
    if (l == 0) {
#pragma unroll
        for (int o = 0; o < 6; ++o) outp[o] = r[o] + bo6[o];
    }
}

// Thread roles (512 threads, 8 waves):
//   [0,134)    L1: dual dot Wg1[0]/Wg2[0] col j      (waves 0-2)
//   [192,326)  L2: dual dot Wg1[1]/Wg2[1] col j-192  (waves 3-5)
//   [384,512)  AB: dual dot Wa/Wb col j-384, owns H[j] (waves 6-7)
//   [384,448)  also proj wave (P1 shadow)
//   448        also norm thread (P1 shadow)
//   0          also x-part writer (P2 shadow)
__global__ __launch_bounds__(512, 2)
void lmsc_kernel(const float* __restrict__ X,  const float* __restrict__ H0,
                 const float* __restrict__ Wg1, const float* __restrict__ bg1,
                 const float* __restrict__ Wg2, const float* __restrict__ bg2,
                 const float* __restrict__ Wa,  const float* __restrict__ ba,
                 const float* __restrict__ Wb,  const float* __restrict__ bb,
                 const float* __restrict__ Wh,  const float* __restrict__ bh,
                 const float* __restrict__ Wo,  const float* __restrict__ bo,
                 float* __restrict__ out)
{
    __shared__ float Xls[Tt * INs];                 // 48 KB: this row's whole input
    __shared__ alignas(16) unsigned LvX[NDW];       // step input:  [x/n (3dw) | H f16 | pad]
    __shared__ alignas(16) unsigned LvB[NDW];       // after layer 1
    __shared__ alignas(16) unsigned LvC[NDW];       // after layer 2
    __shared__ float Hf[HID];                       // f32 H copy for projection
    __shared__ float H0l[STs];
    __shared__ float nrm[2], rnr[2];

    const int tid = threadIdx.x;
    const int n   = blockIdx.x;

    // ---------------- stage X row (coalesced float4) ----------------
    {
        const float4* Xg  = (const float4*)(X + (size_t)n * (Tt * INs));
        float4*       Xl4 = (float4*)Xls;
        for (int i = tid; i < (Tt * INs) / 4; i += 512) Xl4[i] = Xg[i];
    }
    if (tid < STs) H0l[tid] = H0[n * STs + tid];
    if (tid == 0) { LvX[NDW-1] = 0u; LvB[NDW-1] = 0u; LvC[NDW-1] = 0u; }

    // ---------------- per-thread weight columns -> registers (f16, RNE) ----------------
    h2 w1[NDW], w2[NDW];
    float b1 = 0.f, b2 = 0.f;
    {
        const float* Wp1 = nullptr; const float* Wp2 = nullptr; int od = LAY, j = 0;
        if (tid < 134) {
            Wp1 = Wg1;             Wp2 = Wg2;             j = tid;
            b1 = bg1[j];           b2 = bg2[j];
        } else if (tid >= 192 && tid < 326) {
            Wp1 = Wg1 + LAY*LAY;   Wp2 = Wg2 + LAY*LAY;   j = tid - 192;
            b1 = bg1[LAY + j];     b2 = bg2[LAY + j];
        } else if (tid >= 384) {
            Wp1 = Wa; Wp2 = Wb; od = HID;                 j = tid - 384;
            b1 = ba[j];            b2 = bb[j];
        }
        if (Wp1) {
            for (int m = 0; m < NPAIR; ++m) {
                h2 a; a[0] = (_Float16)Wp1[(2*m) * od + j]; a[1] = (_Float16)Wp1[(2*m+1) * od + j];
                h2 b; b[0] = (_Float16)Wp2[(2*m) * od + j]; b[1] = (_Float16)Wp2[(2*m+1) * od + j];
                w1[m] = a; w2[m] = b;
            }
        }
        h2 z; z[0] = (_Float16)0.f; z[1] = (_Float16)0.f;
        w1[NPAIR] = z; w2[NPAIR] = z;
    }
    // projection wave constants
    float wo0[6], wo1[6], bo6[6];
    if (tid >= 384 && tid < 448) {
        int l = tid - 384;
#pragma unroll
        for (int o = 0; o < 6; ++o) {
            wo0[o] = Wo[(2*l)     * OUTs + o];
            wo1[o] = Wo[(2*l + 1) * OUTs + o];
            bo6[o] = bo[o];
        }
    }
    __syncthreads();

    // ---------------- init: S0 = H0 @ Wh + bh ; norm_0 ; x-part ----------------
    float h = 0.f;                                   // AB threads' H-state register
    if (tid >= 384) {
        int j = tid - 384;
        float s = bh[j];
        for (int k = 0; k < STs; ++k) s += H0l[k] * Wh[k * HID + j];
        h = s;
        Hf[j] = s;
        ((_Float16*)LvX)[6 + j] = (_Float16)s;
    }
    if (tid == 448 - 64) {}                          // (keep wave shapes simple)
    if (tid == 448) {
        float s = 0.f;
#pragma unroll
        for (int i = 0; i < 6; ++i) s += Xls[i] * Xls[i];
        float nv = sqrtf(s);
        float rn = rcp_fast(nv);
        nrm[0] = nv; rnr[0] = rn;
        LvX[0] = pack2(Xls[0]*rn, Xls[1]*rn);
        LvX[1] = pack2(Xls[2]*rn, Xls[3]*rn);
        LvX[2] = pack2(Xls[4]*rn, Xls[5]*rn);
    }
    __syncthreads();

    const float LOG2E = 1.4426950408889634f;

#pragma unroll 1
    for (int t = 0; t < Tt; ++t) {
        const int p = t & 1;
        // ---- P1: gated layer 1 (dual dot) ; proj Y[t-1] ; norm for t+1 ----
        if (tid < 134) {
            float s1, s2;
            dotLv2(LvX, w1, w2, b1, b2, s1, s2);
            float v = tanh_fast(s1) * tanh_fast(s2);
            ((_Float16*)LvB)[tid] = (_Float16)v;
        } else if (tid >= 384 && tid < 448) {
            if (t > 0)
                do_proj(Hf, wo0, wo1, bo6, out + ((size_t)n * Tt + (t - 1)) * OUTs, tid - 384);
        } else if (tid == 448 && (t + 1) < Tt) {
            const float* xp = &Xls[(t + 1) * INs];
            float s = 0.f;
#pragma unroll
            for (int i = 0; i < 6; ++i) s += xp[i] * xp[i];
            float nv = sqrtf(s);
            nrm[(t + 1) & 1] = nv;
            rnr[(t + 1) & 1] = rcp_fast(nv);
        }
        __syncthreads();
        // ---- P2: gated layer 2 (dual dot) ; write x-part of LvX for t+1 ----
        if (tid >= 192 && tid < 326) {
            float s1, s2;
            dotLv2(LvB, w1, w2, b1, b2, s1, s2);
            float v = tanh_fast(s1) * tanh_fast(s2);
            ((_Float16*)LvC)[tid - 192] = (_Float16)v;
        } else if (tid == 0 && (t + 1) < Tt) {
            const float* xp = &Xls[(t + 1) * INs];
            float rn = rnr[(t + 1) & 1];
            LvX[0] = pack2(xp[0]*rn, xp[1]*rn);
            LvX[1] = pack2(xp[2]*rn, xp[3]*rn);
            LvX[2] = pack2(xp[4]*rn, xp[5]*rn);
        }
        __syncthreads();
        // ---- P3: alpha/beta dots + H update (state in register) ----
        if (tid >= 384) {
            int j = tid - 384;
            float sA, sB;
            dotLv2(LvC, w1, w2, b1, b2, sA, sB);
            float a = exp2_fast(sA * LOG2E);
            float b = tanh_fast(sB);
            float e = exp2_fast(-a * nrm[p] * LOG2E);
            h = e * (h - b) + b;
            Hf[j] = h;
            ((_Float16*)LvX)[6 + j] = (_Float16)h;
        }
        __syncthreads();
    }
    // ---- epilogue: project Y[T-1] = final H ----
    if (tid >= 384 && tid < 448)
        do_proj(Hf, wo0, wo1, bo6, out + ((size_t)n * Tt + (Tt - 1)) * OUTs, tid - 384);
}

extern "C" void kernel_launch(void* const* d_in, const int* in_sizes, int n_in,
                              void* d_out, int out_size, void* d_ws, size_t ws_size,
                              hipStream_t stream) {
    const float* X   = (const float*)d_in[0];
    const float* H0  = (const float*)d_in[1];
    const float* Wg1 = (const float*)d_in[2];
    const float* bg1 = (const float*)d_in[3];
    const float* Wg2 = (const float*)d_in[4];
    const float* bg2 = (const float*)d_in[5];
    const float* Wa  = (const float*)d_in[6];
    const float* ba  = (const float*)d_in[7];
    const float* Wb  = (const float*)d_in[8];
    const float* bb  = (const float*)d_in[9];
    const float* Wh  = (const float*)d_in[10];
    const float* bh  = (const float*)d_in[11];
    const float* Wo  = (const float*)d_in[12];
    const float* bo  = (const float*)d_in[13];
    float* out = (float*)d_out;

    hipLaunchKernelGGL(lmsc_kernel, dim3(Nb), dim3(512), 0, stream,
                       X, H0, Wg1, bg1, Wg2, bg2, Wa, ba, Wb, bb, Wh, bh, Wo, bo, out);
}

// Round 5
// 3532.122 us; speedup vs baseline: 1.1047x; 1.0014x over previous
//
#include <hip/hip_runtime.h>

// Problem constants (must match reference)
#define Nb   256
#define Tt   2048
#define INs  6
#define HID  128
#define STs  64
#define LAY  134   // INs + HID
#define OUTs 6
#define NPAIR 67   // LAY/2
#define NDW  68    // padded dword count (f16x2 units); last dword is zero pad

typedef _Float16 h2 __attribute__((ext_vector_type(2)));
typedef __fp16  f16x2 __attribute__((ext_vector_type(2)));   // builtin-compatible spelling

__device__ __forceinline__ float exp2_fast(float x) {
#if __has_builtin(__builtin_amdgcn_exp2f)
    return __builtin_amdgcn_exp2f(x);
#else
    return exp2f(x);
#endif
}
__device__ __forceinline__ float rcp_fast(float x) {
#if __has_builtin(__builtin_amdgcn_rcpf)
    return __builtin_amdgcn_rcpf(x);
#else
    return 1.0f / x;
#endif
}
// tanh(x) = 1 - 2/(exp2(2*log2e*x)+1); saturates correctly for |x| large
__device__ __forceinline__ float tanh_fast(float x) {
    float e = exp2_fast(x * 2.8853900817779268f);
    return 1.0f - 2.0f * rcp_fast(e + 1.0f);
}
__device__ __forceinline__ unsigned pack2(float a, float b) {
#if __has_builtin(__builtin_amdgcn_cvt_pkrtz)
    union { f16x2 h; unsigned u; } u;
    u.h = __builtin_amdgcn_cvt_pkrtz(a, b);
    return u.u;
#else
    union { h2 h; unsigned u; } u;
    u.h[0] = (_Float16)a; u.h[1] = (_Float16)b;
    return u.u;
#endif
}
__device__ __forceinline__ h2 as_h2(unsigned v) {
    union { unsigned u; h2 h; } u; u.u = v; return u.h;
}
__device__ __forceinline__ float dot2f(h2 a, h2 b, float c) {
#if __has_builtin(__builtin_amdgcn_fdot2)
    union { h2 h; f16x2 f; } ua, ub;
    ua.h = a; ub.h = b;
    return __builtin_amdgcn_fdot2(ua.f, ub.f, c, false);   // v_dot2_f32_f16
#else
    return c + (float)a[0] * (float)b[0] + (float)a[1] * (float)b[1];
#endif
}

// dual dot over 134 f16 elems (68 packed dwords, last zero pad), shared activation stream
__device__ __forceinline__ void dotLv2(const unsigned* buf, const h2* w1, const h2* w2,
                                       float b1, float b2, float& o1, float& o2) {
    const uint4* b4 = (const uint4*)buf;
    float a0 = 0.f, a1 = 0.f, a2 = 0.f, a3 = 0.f;
    float c0 = 0.f, c1 = 0.f, c2 = 0.f, c3 = 0.f;
#pragma unroll
    for (int m = 0; m < 17; ++m) {
        uint4 v = b4[m];
        h2 vx = as_h2(v.x), vy = as_h2(v.y), vz = as_h2(v.z), vw = as_h2(v.w);
        a0 = dot2f(vx, w1[4*m+0], a0);  c0 = dot2f(vx, w2[4*m+0], c0);
        a1 = dot2f(vy, w1[4*m+1], a1);  c1 = dot2f(vy, w2[4*m+1], c1);
        a2 = dot2f(vz, w1[4*m+2], a2);  c2 = dot2f(vz, w2[4*m+2], c2);
        a3 = dot2f(vw, w1[4*m+3], a3);  c3 = dot2f(vw, w2[4*m+3], c3);
    }
    o1 = ((a0 + a1) + (a2 + a3)) + b1;
    o2 = ((c0 + c1) + (c2 + c3)) + b2;
}

// projection: out[0..5] = H . Wo[:,o] + bo, one full wave, lane l owns H[2l],H[2l+1]
__device__ __forceinline__ void do_proj(const float* Hrow, const float* wo0, const float* wo1,
                                        const float* bo6, float* outp, int l) {
    float hA = Hrow[2*l], hB = Hrow[2*l+1];
    float r[6];
#pragma unroll
    for (int o = 0; o < 6; ++o) r[o] = hA * wo0[o] + hB * wo1[o];
#pragma unroll
    for (int o = 0; o < 6; ++o) {
#pragma unroll
        for (int k = 1; k < 64; k <<= 1) r[o] += __shfl_xor(r[o], k, 64);
    }
    if (l == 0) {
#pragma unroll
        for (int o = 0; o < 6; ++o) outp[o] = r[o] + bo6[o];
    }
}

// Thread roles (512 threads, 8 waves):
//   [0,134)    L1: dual dot Wg1[0]/Wg2[0] col j      (waves 0-2)
//   [192,326)  L2: dual dot Wg1[1]/Wg2[1] col j-192  (waves 3-5)
//   [384,512)  AB: dual dot Wa/Wb col j-384, owns H[j] (waves 6-7)
//   [384,448)  also proj wave (P1 shadow)
//   448        also norm thread (P1 shadow)
//   0          also x-part writer (P2 shadow)
__global__ __launch_bounds__(512, 2)
void lmsc_kernel(const float* __restrict__ X,  const float* __restrict__ H0,
                 const float* __restrict__ Wg1, const float* __restrict__ bg1,
                 const float* __restrict__ Wg2, const float* __restrict__ bg2,
                 const float* __restrict__ Wa,  const float* __restrict__ ba,
                 const float* __restrict__ Wb,  const float* __restrict__ bb,
                 const float* __restrict__ Wh,  const float* __restrict__ bh,
                 const float* __restrict__ Wo,  const float* __restrict__ bo,
                 float* __restrict__ out)
{
    __shared__ float Xls[Tt * INs];                 // 48 KB: this row's whole input
    __shared__ alignas(16) unsigned LvX[NDW];       // step input:  [x/n (3dw) | H f16 | pad]
    __shared__ alignas(16) unsigned LvB[NDW];       // after layer 1
    __shared__ alignas(16) unsigned LvC[NDW];       // after layer 2
    __shared__ float Hf[HID];                       // f32 H copy for projection
    __shared__ float H0l[STs];
    __shared__ float nrm[2], rnr[2];

    const int tid = threadIdx.x;
    const int n   = blockIdx.x;

    // ---------------- stage X row (coalesced float4) ----------------
    {
        const float4* Xg  = (const float4*)(X + (size_t)n * (Tt * INs));
        float4*       Xl4 = (float4*)Xls;
        for (int i = tid; i < (Tt * INs) / 4; i += 512) Xl4[i] = Xg[i];
    }
    if (tid < STs) H0l[tid] = H0[n * STs + tid];
    if (tid == 0) { LvX[NDW-1] = 0u; LvB[NDW-1] = 0u; LvC[NDW-1] = 0u; }

    // ------- per-thread weight columns -> REGISTERS (f16, RNE) -------
    // CRITICAL: the init loop must be fully unrolled so every w1[]/w2[] index is a
    // compile-time constant — otherwise the arrays land in scratch (rule #20;
    // rounds 2/3 had VGPR_Count < array size, i.e. weights were reloaded from
    // scratch inside every dot phase).
    h2 w1[NDW], w2[NDW];
    float b1 = 0.f, b2 = 0.f;
    {
        const float* Wp1 = nullptr; const float* Wp2 = nullptr; int od = LAY, j = 0;
        if (tid < 134) {
            Wp1 = Wg1;             Wp2 = Wg2;             j = tid;
            b1 = bg1[j];           b2 = bg2[j];
        } else if (tid >= 192 && tid < 326) {
            Wp1 = Wg1 + LAY*LAY;   Wp2 = Wg2 + LAY*LAY;   j = tid - 192;
            b1 = bg1[LAY + j];     b2 = bg2[LAY + j];
        } else if (tid >= 384) {
            Wp1 = Wa; Wp2 = Wb; od = HID;                 j = tid - 384;
            b1 = ba[j];            b2 = bb[j];
        }
        if (Wp1) {
#pragma unroll
            for (int m = 0; m < NPAIR; ++m) {
                h2 a; a[0] = (_Float16)Wp1[(2*m) * od + j]; a[1] = (_Float16)Wp1[(2*m+1) * od + j];
                h2 b; b[0] = (_Float16)Wp2[(2*m) * od + j]; b[1] = (_Float16)Wp2[(2*m+1) * od + j];
                w1[m] = a; w2[m] = b;
            }
        } else {
            h2 z; z[0] = (_Float16)0.f; z[1] = (_Float16)0.f;
#pragma unroll
            for (int m = 0; m < NPAIR; ++m) { w1[m] = z; w2[m] = z; }
        }
        h2 z; z[0] = (_Float16)0.f; z[1] = (_Float16)0.f;
        w1[NPAIR] = z; w2[NPAIR] = z;
    }
    // projection wave constants
    float wo0[6], wo1[6], bo6[6];
    if (tid >= 384 && tid < 448) {
        int l = tid - 384;
#pragma unroll
        for (int o = 0; o < 6; ++o) {
            wo0[o] = Wo[(2*l)     * OUTs + o];
            wo1[o] = Wo[(2*l + 1) * OUTs + o];
            bo6[o] = bo[o];
        }
    }
    __syncthreads();

    // ---------------- init: S0 = H0 @ Wh + bh ; norm_0 ; x-part ----------------
    float h = 0.f;                                   // AB threads' H-state register
    if (tid >= 384) {
        int j = tid - 384;
        float s = bh[j];
        for (int k = 0; k < STs; ++k) s += H0l[k] * Wh[k * HID + j];
        h = s;
        Hf[j] = s;
        ((_Float16*)LvX)[6 + j] = (_Float16)s;
    }
    if (tid == 448) {
        float s = 0.f;
#pragma unroll
        for (int i = 0; i < 6; ++i) s += Xls[i] * Xls[i];
        float nv = sqrtf(s);
        float rn = rcp_fast(nv);
        nrm[0] = nv; rnr[0] = rn;
        LvX[0] = pack2(Xls[0]*rn, Xls[1]*rn);
        LvX[1] = pack2(Xls[2]*rn, Xls[3]*rn);
        LvX[2] = pack2(Xls[4]*rn, Xls[5]*rn);
    }
    __syncthreads();

    const float LOG2E = 1.4426950408889634f;

#pragma unroll 1
    for (int t = 0; t < Tt; ++t) {
        const int p = t & 1;
        // ---- P1: gated layer 1 (dual dot) ; proj Y[t-1] ; norm for t+1 ----
        if (tid < 134) {
            float s1, s2;
            dotLv2(LvX, w1, w2, b1, b2, s1, s2);
            float v = tanh_fast(s1) * tanh_fast(s2);
            ((_Float16*)LvB)[tid] = (_Float16)v;
        } else if (tid >= 384 && tid < 448) {
            if (t > 0)
                do_proj(Hf, wo0, wo1, bo6, out + ((size_t)n * Tt + (t - 1)) * OUTs, tid - 384);
        } else if (tid == 448 && (t + 1) < Tt) {
            const float* xp = &Xls[(t + 1) * INs];
            float s = 0.f;
#pragma unroll
            for (int i = 0; i < 6; ++i) s += xp[i] * xp[i];
            float nv = sqrtf(s);
            nrm[(t + 1) & 1] = nv;
            rnr[(t + 1) & 1] = rcp_fast(nv);
        }
        __syncthreads();
        // ---- P2: gated layer 2 (dual dot) ; write x-part of LvX for t+1 ----
        if (tid >= 192 && tid < 326) {
            float s1, s2;
            dotLv2(LvB, w1, w2, b1, b2, s1, s2);
            float v = tanh_fast(s1) * tanh_fast(s2);
            ((_Float16*)LvC)[tid - 192] = (_Float16)v;
        } else if (tid == 0 && (t + 1) < Tt) {
            const float* xp = &Xls[(t + 1) * INs];
            float rn = rnr[(t + 1) & 1];
            LvX[0] = pack2(xp[0]*rn, xp[1]*rn);
            LvX[1] = pack2(xp[2]*rn, xp[3]*rn);
            LvX[2] = pack2(xp[4]*rn, xp[5]*rn);
        }
        __syncthreads();
        // ---- P3: alpha/beta dots + H update (state in register) ----
        if (tid >= 384) {
            int j = tid - 384;
            float sA, sB;
            dotLv2(LvC, w1, w2, b1, b2, sA, sB);
            float a = exp2_fast(sA * LOG2E);
            float b = tanh_fast(sB);
            float e = exp2_fast(-a * nrm[p] * LOG2E);
            h = e * (h - b) + b;
            Hf[j] = h;
            ((_Float16*)LvX)[6 + j] = (_Float16)h;
        }
        __syncthreads();
    }
    // ---- epilogue: project Y[T-1] = final H ----
    if (tid >= 384 && tid < 448)
        do_proj(Hf, wo0, wo1, bo6, out + ((size_t)n * Tt + (Tt - 1)) * OUTs, tid - 384);
}

extern "C" void kernel_launch(void* const* d_in, const int* in_sizes, int n_in,
                              void* d_out, int out_size, void* d_ws, size_t ws_size,
                              hipStream_t stream) {
    const float* X   = (const float*)d_in[0];
    const float* H0  = (const float*)d_in[1];
    const float* Wg1 = (const float*)d_in[2];
    const float* bg1 = (const float*)d_in[3];
    const float* Wg2 = (const float*)d_in[4];
    const float* bg2 = (const float*)d_in[5];
    const float* Wa  = (const float*)d_in[6];
    const float* ba  = (const float*)d_in[7];
    const float* Wb  = (const float*)d_in[8];
    const float* bb  = (const float*)d_in[9];
    const float* Wh  = (const float*)d_in[10];
    const float* bh  = (const float*)d_in[11];
    const float* Wo  = (const float*)d_in[12];
    const float* bo  = (const float*)d_in[13];
    float* out = (float*)d_out;

    hipLaunchKernelGGL(lmsc_kernel, dim3(Nb), dim3(512), 0, stream,
                       X, H0, Wg1, bg1, Wg2, bg2, Wa, ba, Wb, bb, Wh, bh, Wo, bo, out);
}

// Round 6
// 3377.806 us; speedup vs baseline: 1.1552x; 1.0457x over previous
//
#include <hip/hip_runtime.h>

// Problem constants (must match reference)
#define Nb   256
#define Tt   2048
#define INs  6
#define HID  128
#define STs  64
#define LAY  134   // INs + HID
#define OUTs 6
#define NPAIR 67   // LAY/2
#define NDW  68    // padded dword count (f16x2 units); last dword is zero pad

typedef _Float16 h2 __attribute__((ext_vector_type(2)));
typedef __fp16  f16x2 __attribute__((ext_vector_type(2)));   // builtin-compatible spelling
typedef __fp16  f16x8 __attribute__((ext_vector_type(8)));   // 4 VGPRs; pair p = dword p

__device__ __forceinline__ float exp2_fast(float x) {
#if __has_builtin(__builtin_amdgcn_exp2f)
    return __builtin_amdgcn_exp2f(x);
#else
    return exp2f(x);
#endif
}
__device__ __forceinline__ float rcp_fast(float x) {
#if __has_builtin(__builtin_amdgcn_rcpf)
    return __builtin_amdgcn_rcpf(x);
#else
    return 1.0f / x;
#endif
}
// tanh(x) = 1 - 2/(exp2(2*log2e*x)+1); saturates correctly for |x| large
__device__ __forceinline__ float tanh_fast(float x) {
    float e = exp2_fast(x * 2.8853900817779268f);
    return 1.0f - 2.0f * rcp_fast(e + 1.0f);
}
__device__ __forceinline__ unsigned pack2(float a, float b) {
#if __has_builtin(__builtin_amdgcn_cvt_pkrtz)
    union { f16x2 h; unsigned u; } u;
    u.h = __builtin_amdgcn_cvt_pkrtz(a, b);
    return u.u;
#else
    union { h2 h; unsigned u; } u;
    u.h[0] = (_Float16)a; u.h[1] = (_Float16)b;
    return u.u;
#endif
}
// dot of packed-f16 activation dword with an f16x2 weight pair, f32 accumulate
__device__ __forceinline__ float dot2p(unsigned av, f16x2 wv, float c) {
    union { unsigned u; f16x2 f; } ua; ua.u = av;
#if __has_builtin(__builtin_amdgcn_fdot2)
    return __builtin_amdgcn_fdot2(ua.f, wv, c, false);   // v_dot2_f32_f16
#else
    return c + (float)ua.f[0] * (float)wv[0] + (float)ua.f[1] * (float)wv[1];
#endif
}

// ---- X-macro over the 17 weight vector registers (one column = 17 x f16x8) ----
#define WR17(M) M(0) M(1) M(2) M(3) M(4) M(5) M(6) M(7) M(8) M(9) M(10) M(11) M(12) M(13) M(14) M(15) M(16)

#define DECLW(k) f16x8 w##k = {};

// rows 8k..8k+7 of column j, stride od; rows >= LAY are zero pad (k==16 tail)
#define LOADW(k) { \
    f16x8 tmp; \
    _Pragma("unroll") \
    for (int q = 0; q < 8; ++q) { \
        int r = 8 * (k) + q; \
        float f = (r < LAY) ? Wp[r * od + j] : 0.f; \
        tmp[q] = (__fp16)f; \
    } \
    w##k = tmp; \
}

#define DOT4(k) { \
    uint4 v = b4[k]; \
    a0 = dot2p(v.x, __builtin_shufflevector(w##k, w##k, 0, 1), a0); \
    a1 = dot2p(v.y, __builtin_shufflevector(w##k, w##k, 2, 3), a1); \
    a2 = dot2p(v.z, __builtin_shufflevector(w##k, w##k, 4, 5), a2); \
    a3 = dot2p(v.w, __builtin_shufflevector(w##k, w##k, 6, 7), a3); \
}

#define DO_DOT(bufname, sres) { \
    const uint4* b4 = (const uint4*)(bufname); \
    float a0 = 0.f, a1 = 0.f, a2 = 0.f, a3 = 0.f; \
    WR17(DOT4) \
    sres = ((a0 + a1) + (a2 + a3)); \
}

// projection: out[0..5] = H . Wo[:,o] + bo, one full wave, lane l owns H[2l],H[2l+1]
__device__ __forceinline__ void do_proj(const float* Hrow, const float* wo0, const float* wo1,
                                        const float* bo6, float* outp, int l) {
    float hA = Hrow[2*l], hB = Hrow[2*l+1];
    float r[6];
#pragma unroll
    for (int o = 0; o < 6; ++o) r[o] = hA * wo0[o] + hB * wo1[o];
#pragma unroll
    for (int o = 0; o < 6; ++o) {
#pragma unroll
        for (int k = 1; k < 64; k <<= 1) r[o] += __shfl_xor(r[o], k, 64);
    }
    if (l == 0) {
#pragma unroll
        for (int o = 0; o < 6; ++o) outp[o] = r[o] + bo6[o];
    }
}

// Thread roles (1024 threads, 16 waves). Pair (2j, 2j+1) owns column j of the
// phase's two matrices; product combined via __shfl_xor(.,1).
//   [0,268)    L1: Wg1[0] (even) / Wg2[0] (odd), col j = tid>>1
//   [320,588)  L2: Wg1[1] / Wg2[1], col j = (tid-320)>>1
//   [640,896)  AB: Wa (even, owns H[j]) / Wb (odd), col j = (tid-640)>>1
//   [896,960)  proj wave (P1 shadow)
//   1022       norm thread (P1 shadow);  1023: x-part writer (P2 shadow)
__global__ __launch_bounds__(1024, 4)
void lmsc_kernel(const float* __restrict__ X,  const float* __restrict__ H0,
                 const float* __restrict__ Wg1, const float* __restrict__ bg1,
                 const float* __restrict__ Wg2, const float* __restrict__ bg2,
                 const float* __restrict__ Wa,  const float* __restrict__ ba,
                 const float* __restrict__ Wb,  const float* __restrict__ bb,
                 const float* __restrict__ Wh,  const float* __restrict__ bh,
                 const float* __restrict__ Wo,  const float* __restrict__ bo,
                 float* __restrict__ out)
{
    __shared__ float Xls[Tt * INs];                 // 48 KB: this row's whole input
    __shared__ alignas(16) unsigned LvX[NDW];       // step input:  [x/n (3dw) | H f16 | pad]
    __shared__ alignas(16) unsigned LvB[NDW];       // after layer 1
    __shared__ alignas(16) unsigned LvC[NDW];       // after layer 2
    __shared__ float Hf[HID];                       // f32 H copy for projection
    __shared__ float H0l[STs];
    __shared__ float nrm[2], rnr[2];

    const int tid = threadIdx.x;
    const int n   = blockIdx.x;

    const bool isL1 = tid < 268;
    const bool isL2 = (tid >= 320) & (tid < 588);
    const bool isAB = (tid >= 640) & (tid < 896);
    const bool isPJ = (tid >= 896) & (tid < 960);

    // ---------------- stage X row (coalesced float4) ----------------
    {
        const float4* Xg  = (const float4*)(X + (size_t)n * (Tt * INs));
        float4*       Xl4 = (float4*)Xls;
        for (int i = tid; i < (Tt * INs) / 4; i += 1024) Xl4[i] = Xg[i];
    }
    if (tid < STs) H0l[tid] = H0[n * STs + tid];
    if (tid == 1021) { LvX[NDW-1] = 0u; LvB[NDW-1] = 0u; LvC[NDW-1] = 0u; }

    // ------- weight column -> 17 NAMED f16x8 vector registers (SSA, no alloca) -------
    WR17(DECLW)
    float bias = 0.f;
    {
        const float* Wp = nullptr; int od = LAY, j = 0;
        if (isL1) {
            j = tid >> 1;
            Wp = (tid & 1) ? Wg2 : Wg1;
            bias = ((tid & 1) ? bg2 : bg1)[j];
        } else if (isL2) {
            j = (tid - 320) >> 1;
            Wp = ((tid & 1) ? Wg2 : Wg1) + LAY * LAY;
            bias = ((tid & 1) ? bg2 : bg1)[LAY + j];
        } else if (isAB) {
            j = (tid - 640) >> 1;
            Wp = (tid & 1) ? Wb : Wa;  od = HID;
            bias = ((tid & 1) ? bb : ba)[j];
        }
        if (Wp) { WR17(LOADW) }
    }
    // projection wave constants
    float wo0[6], wo1[6], bo6[6];
    if (isPJ) {
        int l = tid - 896;
#pragma unroll
        for (int o = 0; o < 6; ++o) {
            wo0[o] = Wo[(2*l)     * OUTs + o];
            wo1[o] = Wo[(2*l + 1) * OUTs + o];
            bo6[o] = bo[o];
        }
    }
    __syncthreads();

    // ---------------- init: S0 = H0 @ Wh + bh ; norm_0 ; x-part ----------------
    float h = 0.f;                                   // even-AB threads' H-state register
    if (isAB && !(tid & 1)) {
        int j = (tid - 640) >> 1;
        float s = bh[j];
        for (int k = 0; k < STs; ++k) s += H0l[k] * Wh[k * HID + j];
        h = s;
        Hf[j] = s;
        ((_Float16*)LvX)[6 + j] = (_Float16)s;
    }
    if (tid == 1022) {
        float s = 0.f;
#pragma unroll
        for (int i = 0; i < 6; ++i) s += Xls[i] * Xls[i];
        float nv = sqrtf(s);
        float rn = rcp_fast(nv);
        nrm[0] = nv; rnr[0] = rn;
        LvX[0] = pack2(Xls[0]*rn, Xls[1]*rn);
        LvX[1] = pack2(Xls[2]*rn, Xls[3]*rn);
        LvX[2] = pack2(Xls[4]*rn, Xls[5]*rn);
    }
    __syncthreads();

    const float LOG2E = 1.4426950408889634f;

#pragma unroll 1
    for (int t = 0; t < Tt; ++t) {
        const int p = t & 1;
        // ---- P1: gated layer 1 ; proj Y[t-1] ; norm for t+1 ----
        if (isL1) {
            float s; DO_DOT(LvX, s); s += bias;
            float tn = tanh_fast(s);
            float to = __shfl_xor(tn, 1, 64);
            if (!(tid & 1)) ((_Float16*)LvB)[tid >> 1] = (_Float16)(tn * to);
        } else if (isPJ) {
            if (t > 0)
                do_proj(Hf, wo0, wo1, bo6, out + ((size_t)n * Tt + (t - 1)) * OUTs, tid - 896);
        } else if (tid == 1022 && (t + 1) < Tt) {
            const float* xp = &Xls[(t + 1) * INs];
            float s = 0.f;
#pragma unroll
            for (int i = 0; i < 6; ++i) s += xp[i] * xp[i];
            float nv = sqrtf(s);
            nrm[(t + 1) & 1] = nv;
            rnr[(t + 1) & 1] = rcp_fast(nv);
        }
        __syncthreads();
        // ---- P2: gated layer 2 ; write x-part of LvX for t+1 ----
        if (isL2) {
            float s; DO_DOT(LvB, s); s += bias;
            float tn = tanh_fast(s);
            float to = __shfl_xor(tn, 1, 64);
            if (!(tid & 1)) ((_Float16*)LvC)[(tid - 320) >> 1] = (_Float16)(tn * to);
        } else if (tid == 1023 && (t + 1) < Tt) {
            const float* xp = &Xls[(t + 1) * INs];
            float rn = rnr[(t + 1) & 1];
            LvX[0] = pack2(xp[0]*rn, xp[1]*rn);
            LvX[1] = pack2(xp[2]*rn, xp[3]*rn);
            LvX[2] = pack2(xp[4]*rn, xp[5]*rn);
        }
        __syncthreads();
        // ---- P3: alpha/beta + H update (H state in even lane's register) ----
        if (isAB) {
            float s; DO_DOT(LvC, s); s += bias;
            float bown = tanh_fast(s);                 // odd lane: beta
            float beta = __shfl_xor(bown, 1, 64);      // even lane receives beta
            if (!(tid & 1)) {
                int j = (tid - 640) >> 1;
                float alpha = exp2_fast(s * LOG2E);    // even lane: alpha = exp(sA)
                float e = exp2_fast(-alpha * nrm[p] * LOG2E);
                h = e * (h - beta) + beta;
                Hf[j] = h;
                ((_Float16*)LvX)[6 + j] = (_Float16)h;
            }
        }
        __syncthreads();
    }
    // ---- epilogue: project Y[T-1] = final H ----
    if (isPJ)
        do_proj(Hf, wo0, wo1, bo6, out + ((size_t)n * Tt + (Tt - 1)) * OUTs, tid - 896);
}

extern "C" void kernel_launch(void* const* d_in, const int* in_sizes, int n_in,
                              void* d_out, int out_size, void* d_ws, size_t ws_size,
                              hipStream_t stream) {
    const float* X   = (const float*)d_in[0];
    const float* H0  = (const float*)d_in[1];
    const float* Wg1 = (const float*)d_in[2];
    const float* bg1 = (const float*)d_in[3];
    const float* Wg2 = (const float*)d_in[4];
    const float* bg2 = (const float*)d_in[5];
    const float* Wa  = (const float*)d_in[6];
    const float* ba  = (const float*)d_in[7];
    const float* Wb  = (const float*)d_in[8];
    const float* bb  = (const float*)d_in[9];
    const float* Wh  = (const float*)d_in[10];
    const float* bh  = (const float*)d_in[11];
    const float* Wo  = (const float*)d_in[12];
    const float* bo  = (const float*)d_in[13];
    float* out = (float*)d_out;

    hipLaunchKernelGGL(lmsc_kernel, dim3(Nb), dim3(1024), 0, stream,
                       X, H0, Wg1, bg1, Wg2, bg2, Wa, ba, Wb, bb, Wh, bh, Wo, bo, out);
}

// Round 7
// 3373.523 us; speedup vs baseline: 1.1566x; 1.0013x over previous
//
#include <hip/hip_runtime.h>

// Problem constants (must match reference)
#define Nb   256
#define Tt   2048
#define INs  6
#define HID  128
#define STs  64
#define LAY  134   // INs + HID
#define OUTs 6
#define NPAIR 67   // LAY/2
#define NDW  68    // padded dword count (f16x2 units); last dword is zero pad

typedef _Float16 h2 __attribute__((ext_vector_type(2)));
typedef __fp16  f16x2 __attribute__((ext_vector_type(2)));   // builtin-compatible spelling
typedef __fp16  f16x8 __attribute__((ext_vector_type(8)));   // 4 VGPRs; pair p = dword p

__device__ __forceinline__ float exp2_fast(float x) {
#if __has_builtin(__builtin_amdgcn_exp2f)
    return __builtin_amdgcn_exp2f(x);
#else
    return exp2f(x);
#endif
}
__device__ __forceinline__ float rcp_fast(float x) {
#if __has_builtin(__builtin_amdgcn_rcpf)
    return __builtin_amdgcn_rcpf(x);
#else
    return 1.0f / x;
#endif
}
// tanh(x) = 1 - 2/(exp2(2*log2e*x)+1); saturates correctly for |x| large
__device__ __forceinline__ float tanh_fast(float x) {
    float e = exp2_fast(x * 2.8853900817779268f);
    return 1.0f - 2.0f * rcp_fast(e + 1.0f);
}
__device__ __forceinline__ unsigned pack2(float a, float b) {
#if __has_builtin(__builtin_amdgcn_cvt_pkrtz)
    union { f16x2 h; unsigned u; } u;
    u.h = __builtin_amdgcn_cvt_pkrtz(a, b);
    return u.u;
#else
    union { h2 h; unsigned u; } u;
    u.h[0] = (_Float16)a; u.h[1] = (_Float16)b;
    return u.u;
#endif
}
// dot of packed-f16 activation dword with an f16x2 weight pair, f32 accumulate
__device__ __forceinline__ float dot2p(unsigned av, f16x2 wv, float c) {
    union { unsigned u; f16x2 f; } ua; ua.u = av;
#if __has_builtin(__builtin_amdgcn_fdot2)
    return __builtin_amdgcn_fdot2(ua.f, wv, c, false);   // v_dot2_f32_f16
#else
    return c + (float)ua.f[0] * (float)wv[0] + (float)ua.f[1] * (float)wv[1];
#endif
}

// ---- X-macro over the 17 weight vector registers (one column = 17 x f16x8) ----
#define WR17(M) M(0) M(1) M(2) M(3) M(4) M(5) M(6) M(7) M(8) M(9) M(10) M(11) M(12) M(13) M(14) M(15) M(16)

#define DECLW(k) f16x8 w##k = {};

// rows 8k..8k+7 of column j, stride od; rows >= LAY are zero pad (k==16 tail)
#define LOADW(k) { \
    f16x8 tmp; \
    _Pragma("unroll") \
    for (int q = 0; q < 8; ++q) { \
        int r = 8 * (k) + q; \
        float f = (r < LAY) ? Wp[r * od + j] : 0.f; \
        tmp[q] = (__fp16)f; \
    } \
    w##k = tmp; \
}

#define DOT4(k) { \
    uint4 v = b4[k]; \
    a0 = dot2p(v.x, __builtin_shufflevector(w##k, w##k, 0, 1), a0); \
    a1 = dot2p(v.y, __builtin_shufflevector(w##k, w##k, 2, 3), a1); \
    a2 = dot2p(v.z, __builtin_shufflevector(w##k, w##k, 4, 5), a2); \
    a3 = dot2p(v.w, __builtin_shufflevector(w##k, w##k, 6, 7), a3); \
}

#define DO_DOT(bufname, sres) { \
    const uint4* b4 = (const uint4*)(bufname); \
    float a0 = 0.f, a1 = 0.f, a2 = 0.f, a3 = 0.f; \
    WR17(DOT4) \
    sres = ((a0 + a1) + (a2 + a3)); \
}

// projection: out[0..5] = H . Wo[:,o] + bo, one full wave, lane l owns H[2l],H[2l+1]
__device__ __forceinline__ void do_proj(const float* Hrow, const float* wo0, const float* wo1,
                                        const float* bo6, float* outp, int l) {
    float hA = Hrow[2*l], hB = Hrow[2*l+1];
    float r[6];
#pragma unroll
    for (int o = 0; o < 6; ++o) r[o] = hA * wo0[o] + hB * wo1[o];
#pragma unroll
    for (int o = 0; o < 6; ++o) {
#pragma unroll
        for (int k = 1; k < 64; k <<= 1) r[o] += __shfl_xor(r[o], k, 64);
    }
    if (l == 0) {
#pragma unroll
        for (int o = 0; o < 6; ++o) outp[o] = r[o] + bo6[o];
    }
}

// Thread roles (1024 threads, 16 waves). Pair (2j, 2j+1) owns column j of the
// phase's two matrices; product combined via __shfl_xor(.,1).
//   [0,268)    L1: Wg1[0] (even) / Wg2[0] (odd), col j = tid>>1
//   [320,588)  L2: Wg1[1] / Wg2[1], col j = (tid-320)>>1
//   [640,896)  AB: Wa (even, owns H[j]) / Wb (odd), col j = (tid-640)>>1
//   [896,960)  proj wave (P1 shadow)
//   1022       norm thread (P1 shadow);  1023: x-part writer (P2 shadow)
//
// amdgpu_waves_per_eu(4,4): grid is 256 blocks = 1 block/CU = 4 waves/EU.
// Without the max clamp the backend's occupancy heuristic targets 8 waves/EU
// and SPILLS the 68-VGPR weight set to scratch (round 6: VGPR=64, FETCH/WRITE
// inflated by spill traffic) — for occupancy that can never materialize.
__global__ __launch_bounds__(1024) __attribute__((amdgpu_waves_per_eu(4, 4)))
void lmsc_kernel(const float* __restrict__ X,  const float* __restrict__ H0,
                 const float* __restrict__ Wg1, const float* __restrict__ bg1,
                 const float* __restrict__ Wg2, const float* __restrict__ bg2,
                 const float* __restrict__ Wa,  const float* __restrict__ ba,
                 const float* __restrict__ Wb,  const float* __restrict__ bb,
                 const float* __restrict__ Wh,  const float* __restrict__ bh,
                 const float* __restrict__ Wo,  const float* __restrict__ bo,
                 float* __restrict__ out)
{
    __shared__ float Xls[Tt * INs];                 // 48 KB: this row's whole input
    __shared__ alignas(16) unsigned LvX[NDW];       // step input:  [x/n (3dw) | H f16 | pad]
    __shared__ alignas(16) unsigned LvB[NDW];       // after layer 1
    __shared__ alignas(16) unsigned LvC[NDW];       // after layer 2
    __shared__ float Hf[HID];                       // f32 H copy for projection
    __shared__ float H0l[STs];
    __shared__ float nrm[2], rnr[2];

    const int tid = threadIdx.x;
    const int n   = blockIdx.x;

    const bool isL1 = tid < 268;
    const bool isL2 = (tid >= 320) & (tid < 588);
    const bool isAB = (tid >= 640) & (tid < 896);
    const bool isPJ = (tid >= 896) & (tid < 960);

    // ---------------- stage X row (coalesced float4) ----------------
    {
        const float4* Xg  = (const float4*)(X + (size_t)n * (Tt * INs));
        float4*       Xl4 = (float4*)Xls;
        for (int i = tid; i < (Tt * INs) / 4; i += 1024) Xl4[i] = Xg[i];
    }
    if (tid < STs) H0l[tid] = H0[n * STs + tid];
    if (tid == 1021) { LvX[NDW-1] = 0u; LvB[NDW-1] = 0u; LvC[NDW-1] = 0u; }

    // ------- weight column -> 17 NAMED f16x8 vector registers (SSA, no alloca) -------
    WR17(DECLW)
    float bias = 0.f;
    {
        const float* Wp = nullptr; int od = LAY, j = 0;
        if (isL1) {
            j = tid >> 1;
            Wp = (tid & 1) ? Wg2 : Wg1;
            bias = ((tid & 1) ? bg2 : bg1)[j];
        } else if (isL2) {
            j = (tid - 320) >> 1;
            Wp = ((tid & 1) ? Wg2 : Wg1) + LAY * LAY;
            bias = ((tid & 1) ? bg2 : bg1)[LAY + j];
        } else if (isAB) {
            j = (tid - 640) >> 1;
            Wp = (tid & 1) ? Wb : Wa;  od = HID;
            bias = ((tid & 1) ? bb : ba)[j];
        }
        if (Wp) { WR17(LOADW) }
    }
    // projection wave constants
    float wo0[6], wo1[6], bo6[6];
    if (isPJ) {
        int l = tid - 896;
#pragma unroll
        for (int o = 0; o < 6; ++o) {
            wo0[o] = Wo[(2*l)     * OUTs + o];
            wo1[o] = Wo[(2*l + 1) * OUTs + o];
            bo6[o] = bo[o];
        }
    }
    __syncthreads();

    // ---------------- init: S0 = H0 @ Wh + bh ; norm_0 ; x-part ----------------
    float h = 0.f;                                   // even-AB threads' H-state register
    if (isAB && !(tid & 1)) {
        int j = (tid - 640) >> 1;
        float s = bh[j];
        for (int k = 0; k < STs; ++k) s += H0l[k] * Wh[k * HID + j];
        h = s;
        Hf[j] = s;
        ((_Float16*)LvX)[6 + j] = (_Float16)s;
    }
    if (tid == 1022) {
        float s = 0.f;
#pragma unroll
        for (int i = 0; i < 6; ++i) s += Xls[i] * Xls[i];
        float nv = sqrtf(s);
        float rn = rcp_fast(nv);
        nrm[0] = nv; rnr[0] = rn;
        LvX[0] = pack2(Xls[0]*rn, Xls[1]*rn);
        LvX[1] = pack2(Xls[2]*rn, Xls[3]*rn);
        LvX[2] = pack2(Xls[4]*rn, Xls[5]*rn);
    }
    __syncthreads();

    const float LOG2E = 1.4426950408889634f;

#pragma unroll 1
    for (int t = 0; t < Tt; ++t) {
        const int p = t & 1;
        // ---- P1: gated layer 1 ; proj Y[t-1] ; norm for t+1 ----
        if (isL1) {
            float s; DO_DOT(LvX, s); s += bias;
            float tn = tanh_fast(s);
            float to = __shfl_xor(tn, 1, 64);
            if (!(tid & 1)) ((_Float16*)LvB)[tid >> 1] = (_Float16)(tn * to);
        } else if (isPJ) {
            if (t > 0)
                do_proj(Hf, wo0, wo1, bo6, out + ((size_t)n * Tt + (t - 1)) * OUTs, tid - 896);
        } else if (tid == 1022 && (t + 1) < Tt) {
            const float* xp = &Xls[(t + 1) * INs];
            float s = 0.f;
#pragma unroll
            for (int i = 0; i < 6; ++i) s += xp[i] * xp[i];
            float nv = sqrtf(s);
            nrm[(t + 1) & 1] = nv;
            rnr[(t + 1) & 1] = rcp_fast(nv);
        }
        __syncthreads();
        // ---- P2: gated layer 2 ; write x-part of LvX for t+1 ----
        if (isL2) {
            float s; DO_DOT(LvB, s); s += bias;
            float tn = tanh_fast(s);
            float to = __shfl_xor(tn, 1, 64);
            if (!(tid & 1)) ((_Float16*)LvC)[(tid - 320) >> 1] = (_Float16)(tn * to);
        } else if (tid == 1023 && (t + 1) < Tt) {
            const float* xp = &Xls[(t + 1) * INs];
            float rn = rnr[(t + 1) & 1];
            LvX[0] = pack2(xp[0]*rn, xp[1]*rn);
            LvX[1] = pack2(xp[2]*rn, xp[3]*rn);
            LvX[2] = pack2(xp[4]*rn, xp[5]*rn);
        }
        __syncthreads();
        // ---- P3: alpha/beta + H update (H state in even lane's register) ----
        if (isAB) {
            float s; DO_DOT(LvC, s); s += bias;
            float bown = tanh_fast(s);                 // odd lane: beta
            float beta = __shfl_xor(bown, 1, 64);      // even lane receives beta
            if (!(tid & 1)) {
                int j = (tid - 640) >> 1;
                float alpha = exp2_fast(s * LOG2E);    // even lane: alpha = exp(sA)
                float e = exp2_fast(-alpha * nrm[p] * LOG2E);
                h = e * (h - beta) + beta;
                Hf[j] = h;
                ((_Float16*)LvX)[6 + j] = (_Float16)h;
            }
        }
        __syncthreads();
    }
    // ---- epilogue: project Y[T-1] = final H ----
    if (isPJ)
        do_proj(Hf, wo0, wo1, bo6, out + ((size_t)n * Tt + (Tt - 1)) * OUTs, tid - 896);
}

extern "C" void kernel_launch(void* const* d_in, const int* in_sizes, int n_in,
                              void* d_out, int out_size, void* d_ws, size_t ws_size,
                              hipStream_t stream) {
    const float* X   = (const float*)d_in[0];
    const float* H0  = (const float*)d_in[1];
    const float* Wg1 = (const float*)d_in[2];
    const float* bg1 = (const float*)d_in[3];
    const float* Wg2 = (const float*)d_in[4];
    const float* bg2 = (const float*)d_in[5];
    const float* Wa  = (const float*)d_in[6];
    const float* ba  = (const float*)d_in[7];
    const float* Wb  = (const float*)d_in[8];
    const float* bb  = (const float*)d_in[9];
    const float* Wh  = (const float*)d_in[10];
    const float* bh  = (const float*)d_in[11];
    const float* Wo  = (const float*)d_in[12];
    const float* bo  = (const float*)d_in[13];
    float* out = (float*)d_out;

    hipLaunchKernelGGL(lmsc_kernel, dim3(Nb), dim3(1024), 0, stream,
                       X, H0, Wg1, bg1, Wg2, bg2, Wa, ba, Wb, bb, Wh, bh, Wo, bo, out);
}